// Round 5
// baseline (426.981 us; speedup 1.0000x reference)
//
#include <hip/hip_runtime.h>
#include <cstdint>
#include <cstddef>

#define B_   2
#define S_   21760
#define M_   (B_ * S_)     // 43520
#define D_   256
#define DFF_ 1024
#define EPS_ 1e-5f

typedef __attribute__((ext_vector_type(8))) short short8;
typedef __attribute__((ext_vector_type(4))) float f32x4;
typedef __attribute__((ext_vector_type(2))) float f32x2;

__device__ __forceinline__ ushort f2bf(float f) {
    uint x = __float_as_uint(f);
    return (ushort)((x + 0x7fffu + ((x >> 16) & 1u)) >> 16);
}
__device__ __forceinline__ float bf2f(ushort u) {
    return __uint_as_float(((uint)u) << 16);
}

// ---------------------------------------------------------------------------
// One-shot weight transpose+convert for ALL weights + off/attn bias concat.
// ---------------------------------------------------------------------------
__global__ __launch_bounds__(256) void wconv_all(
    const float* __restrict__ Wval, const float* __restrict__ Woff,
    const float* __restrict__ Wattn, const float* __restrict__ Wout,
    const float* __restrict__ Wff1, const float* __restrict__ Wff2,
    const float* __restrict__ boff, const float* __restrict__ battn,
    ushort* __restrict__ WT, float* __restrict__ bias_oa)
{
    const int i = blockIdx.x * 256 + threadIdx.x;
    if (i < 65536) {
        const int n = i >> 8, k = i & 255;
        WT[i] = f2bf(Wval[(size_t)k * 256 + n]);
    } else if (i < 163840) {
        const int j = i - 65536;
        const int n = j >> 8, k = j & 255;
        WT[i] = (n < 256) ? f2bf(Woff[(size_t)k * 256 + n])
                          : f2bf(Wattn[(size_t)k * 128 + (n - 256)]);
    } else if (i < 229376) {
        const int j = i - 163840;
        const int n = j >> 8, k = j & 255;
        WT[i] = f2bf(Wout[(size_t)k * 256 + n]);
    } else if (i < 491520) {
        const int j = i - 229376;
        const int n = j >> 8, k = j & 255;
        WT[i] = f2bf(Wff1[(size_t)k * 1024 + n]);
    } else if (i < 753664) {
        const int j = i - 491520;
        const int n = j >> 10, k = j & 1023;
        WT[i] = f2bf(Wff2[(size_t)k * 256 + n]);
    } else if (i < 753664 + 384) {
        const int j = i - 753664;
        bias_oa[j] = (j < 256) ? boff[j] : battn[j - 256];
    }
}

// ---------------------------------------------------------------------------
// src_bf = bf16(src); q_bf = bf16(src + pos)
// ---------------------------------------------------------------------------
__global__ __launch_bounds__(256) void cvt_pair(
    const float* __restrict__ src, const float* __restrict__ pos,
    ushort* __restrict__ sb, ushort* __restrict__ qb)
{
    const size_t i = ((size_t)blockIdx.x * 256 + threadIdx.x) * 4;
    if (i >= (size_t)M_ * 256) return;
    const float4 s = *(const float4*)(src + i);
    const float4 p = *(const float4*)(pos + i);
    ushort4 so, qo;
    so.x = f2bf(s.x); so.y = f2bf(s.y); so.z = f2bf(s.z); so.w = f2bf(s.w);
    qo.x = f2bf(s.x + p.x); qo.y = f2bf(s.y + p.y);
    qo.z = f2bf(s.z + p.z); qo.w = f2bf(s.w + p.w);
    *(ushort4*)(sb + i) = so;
    *(ushort4*)(qb + i) = qo;
}

// ---------------------------------------------------------------------------
// bf16 MFMA GEMM: 128x128 tile, BK=32, 4 waves, 4x4 16x16x32 fragments.
// mode 0: C row-major [M][N] bf16.
// mode 2: C = fp8 e4m3, head-major value layout [b][h][loc][32].
// ---------------------------------------------------------------------------
__global__ __launch_bounds__(256) void mgemm(
    const ushort* __restrict__ A, const ushort* __restrict__ WT,
    const float* __restrict__ bias, ushort* __restrict__ C,
    int M, int N, int K, int relu, int mode)
{
    __shared__ __align__(16) ushort Als[128 * 32];
    __shared__ __align__(16) ushort Bls[128 * 32];

    const int tid = threadIdx.x;
    const int wv = tid >> 6, ln = tid & 63;
    const int m0 = blockIdx.y << 7, n0 = blockIdx.x << 7;
    const int wm = wv >> 1, wn = wv & 1;

    const int lrow = ln >> 2, lcol = (ln & 3) * 8;

    f32x4 acc[4][4];
    const f32x4 zz = {0.f, 0.f, 0.f, 0.f};
    #pragma unroll
    for (int i = 0; i < 4; i++)
        #pragma unroll
        for (int j = 0; j < 4; j++) acc[i][j] = zz;

    for (int k0 = 0; k0 < K; k0 += 32) {
        __syncthreads();
        #pragma unroll
        for (int r = 0; r < 2; ++r) {
            const int c = r * 4 + wv;
            const ushort* ga = A + (size_t)(m0 + c * 16 + lrow) * K + k0 + lcol;
            __builtin_amdgcn_global_load_lds(
                (const __attribute__((address_space(1))) uint*)ga,
                (__attribute__((address_space(3))) uint*)(Als + c * 512), 16, 0, 0);
            const ushort* gb = WT + (size_t)(n0 + c * 16 + lrow) * K + k0 + lcol;
            __builtin_amdgcn_global_load_lds(
                (const __attribute__((address_space(1))) uint*)gb,
                (__attribute__((address_space(3))) uint*)(Bls + c * 512), 16, 0, 0);
        }
        __syncthreads();

        const int fr = ln & 15, kb = (ln >> 4) * 8;
        short8 af[4], bfr[4];
        #pragma unroll
        for (int i = 0; i < 4; i++)
            af[i] = *(const short8*)&Als[(wm * 64 + i * 16 + fr) * 32 + kb];
        #pragma unroll
        for (int j = 0; j < 4; j++)
            bfr[j] = *(const short8*)&Bls[(wn * 64 + j * 16 + fr) * 32 + kb];
        #pragma unroll
        for (int i = 0; i < 4; i++)
            #pragma unroll
            for (int j = 0; j < 4; j++)
                acc[i][j] = __builtin_amdgcn_mfma_f32_16x16x32_bf16(
                    af[i], bfr[j], acc[i][j], 0, 0, 0);
    }

    uint8_t* C8 = (uint8_t*)C;
    const int fr = ln & 15, rq = (ln >> 4) * 4;
    #pragma unroll
    for (int j = 0; j < 4; j++) {
        const int col = n0 + wn * 64 + j * 16 + fr;
        const float bv = bias[col];
        #pragma unroll
        for (int i = 0; i < 4; i++) {
            #pragma unroll
            for (int r = 0; r < 4; r++) {
                const int row = m0 + wm * 64 + i * 16 + rq + r;
                float v = acc[i][j][r] + bv;
                if (relu) v = fmaxf(v, 0.f);
                if (mode == 0) {
                    C[(size_t)row * N + col] = f2bf(v);
                } else {
                    const int bb = (row >= S_) ? 1 : 0;
                    const int loc = row - bb * S_;
                    const int hh = col >> 5, ch = col & 31;
                    const int pk = __builtin_amdgcn_cvt_pk_fp8_f32(v, v, 0, false);
                    C8[((size_t)(bb * 8 + hh) * S_ + loc) * 32 + ch] = (uint8_t)(pk & 0xff);
                }
            }
        }
    }
}

// ---------------------------------------------------------------------------
// Deformable sampling v5: owner-LEVEL lanes, shuffle-free load path.
// Block = 8 queries x 32 lanes; 4-lane group per (q,h); lane cg owns level cg:
// computes its 4 samples' math locally and gathers ALL 32 channels of its 16
// corners (2x16B independent loads each). Partial 32-ch sums combined by a
// 2-stage shfl_xor butterfly at the end; lane stores its 8-ch slice.
// XCD-chunked blockIdx swizzle for value-L2 locality (nwg=5440 % 8 == 0).
// ---------------------------------------------------------------------------
__global__ __launch_bounds__(256) void sample5(
    const uint8_t* __restrict__ value, const ushort* __restrict__ offaw,
    const float* __restrict__ refp, ushort* __restrict__ samp)
{
    // bijective XCD swizzle: XCD x owns contiguous chunk of 680 blocks
    const int nwg = M_ / 8;                       // 5440
    const int bid = blockIdx.x;
    const int wg = (bid & 7) * (nwg >> 3) + (bid >> 3);

    const int t = threadIdx.x;
    const int q = wg * 8 + (t >> 5);
    const int w = t & 31;
    const int h = w >> 2, cg = w & 3;
    const int b = q / S_;

    // own level: Wl = Hl = 128>>cg
    const int Wl = 128 >> cg;
    const float fW = (float)Wl;
    const int st = (cg == 0) ? 0 : (cg == 1) ? 16384 : (cg == 2) ? 20480 : 21504;

    // group softmax (each lane holds its level's 4 logits)
    const ushort* awq = offaw + (size_t)q * 384 + 256 + h * 16 + cg * 4;
    const uint2 lg = *(const uint2*)awq;
    float l0 = bf2f((ushort)(lg.x & 0xffff)), l1 = bf2f((ushort)(lg.x >> 16));
    float l2 = bf2f((ushort)(lg.y & 0xffff)), l3 = bf2f((ushort)(lg.y >> 16));
    float mx = fmaxf(fmaxf(l0, l1), fmaxf(l2, l3));
    mx = fmaxf(mx, __shfl_xor(mx, 1));
    mx = fmaxf(mx, __shfl_xor(mx, 2));
    const float e0 = __expf(l0 - mx), e1 = __expf(l1 - mx);
    const float e2 = __expf(l2 - mx), e3 = __expf(l3 - mx);
    float sm = e0 + e1 + e2 + e3;
    sm += __shfl_xor(sm, 1);
    sm += __shfl_xor(sm, 2);
    const float inv = 1.f / sm;
    const float aj[4] = {e0 * inv, e1 * inv, e2 * inv, e3 * inv};

    // local math for own 4 samples (no shuffles)
    const ushort* ofq = offaw + (size_t)q * 384 + h * 32 + cg * 8;
    const uint4 of = *(const uint4*)ofq;
    const float rx = refp[(size_t)q * 8 + cg * 2];
    const float ry = refp[(size_t)q * 8 + cg * 2 + 1];
    const uint ou[4] = {of.x, of.y, of.z, of.w};

    float wt[4][4];
    int   ix[4][4];
    #pragma unroll
    for (int j = 0; j < 4; j++) {
        const float ox = bf2f((ushort)(ou[j] & 0xffff));
        const float oy = bf2f((ushort)(ou[j] >> 16));
        const float x = fmaf(rx, fW, ox) - 0.5f;
        const float y = fmaf(ry, fW, oy) - 0.5f;
        const float fx0 = floorf(x), fy0 = floorf(y);
        const float dx = x - fx0, dy = y - fy0;
        const int x0 = (int)fx0, y0 = (int)fy0;
        const float a = aj[j];
        const float cwv[4] = {a * (1.f - dx) * (1.f - dy), a * dx * (1.f - dy),
                              a * (1.f - dx) * dy,          a * dx * dy};
        const int cx[4] = {x0, x0 + 1, x0, x0 + 1};
        const int cy[4] = {y0, y0, y0 + 1, y0 + 1};
        #pragma unroll
        for (int c = 0; c < 4; c++) {
            const bool ok = (cx[c] >= 0) & (cx[c] < Wl) & (cy[c] >= 0) & (cy[c] < Wl);
            wt[j][c] = ok ? cwv[c] : 0.f;
            const int xc = min(max(cx[c], 0), Wl - 1);
            const int yc = min(max(cy[c], 0), Wl - 1);
            ix[j][c] = (st + yc * Wl + xc) * 32;
        }
    }

    // gather own 16 corners, all 32 channels; fully independent loads
    const uint8_t* vb = value + (size_t)(b * 8 + h) * S_ * 32;
    f32x2 acc[16];
    #pragma unroll
    for (int k = 0; k < 16; k++) acc[k] = (f32x2){0.f, 0.f};

    #pragma unroll
    for (int j = 0; j < 4; j++) {
        #pragma unroll
        for (int c = 0; c < 4; c++) {
            const float wv = wt[j][c];
            const f32x2 w2 = {wv, wv};
            const uint8_t* p = vb + ix[j][c];
            const uint4 u0 = *(const uint4*)p;
            const uint4 u1 = *(const uint4*)(p + 16);
            const uint du[8] = {u0.x, u0.y, u0.z, u0.w, u1.x, u1.y, u1.z, u1.w};
            #pragma unroll
            for (int d2 = 0; d2 < 8; d2++) {
                acc[2 * d2]     += w2 * __builtin_amdgcn_cvt_pk_f32_fp8((int)du[d2], false);
                acc[2 * d2 + 1] += w2 * __builtin_amdgcn_cvt_pk_f32_fp8((int)du[d2], true);
            }
        }
    }

    // butterfly across the 4-lane group: every lane gets full 32-ch sums
    #pragma unroll
    for (int k = 0; k < 16; k++) {
        acc[k].x += __shfl_xor(acc[k].x, 1);
        acc[k].y += __shfl_xor(acc[k].y, 1);
    }
    #pragma unroll
    for (int k = 0; k < 16; k++) {
        acc[k].x += __shfl_xor(acc[k].x, 2);
        acc[k].y += __shfl_xor(acc[k].y, 2);
    }

    // lane stores its 8-channel slice (compile-time indexed per branch)
    f32x2 r0, r1, r2, r3;
    if (cg == 0)      { r0 = acc[0];  r1 = acc[1];  r2 = acc[2];  r3 = acc[3];  }
    else if (cg == 1) { r0 = acc[4];  r1 = acc[5];  r2 = acc[6];  r3 = acc[7];  }
    else if (cg == 2) { r0 = acc[8];  r1 = acc[9];  r2 = acc[10]; r3 = acc[11]; }
    else              { r0 = acc[12]; r1 = acc[13]; r2 = acc[14]; r3 = acc[15]; }

    uint4 o;
    o.x = (uint)f2bf(r0.x) | ((uint)f2bf(r0.y) << 16);
    o.y = (uint)f2bf(r1.x) | ((uint)f2bf(r1.y) << 16);
    o.z = (uint)f2bf(r2.x) | ((uint)f2bf(r2.y) << 16);
    o.w = (uint)f2bf(r3.x) | ((uint)f2bf(r3.y) << 16);
    *(uint4*)(samp + (size_t)q * 256 + h * 32 + cg * 8) = o;
}

// ---------------------------------------------------------------------------
// LayerNorm over D=256: v = (a32 ? a32 : bf(a16)) + bf(r16); out f32 or bf16.
// ---------------------------------------------------------------------------
__global__ __launch_bounds__(256) void ln_mix(
    const float* __restrict__ a32, const ushort* __restrict__ a16,
    const ushort* __restrict__ r16,
    const float* __restrict__ g, const float* __restrict__ be,
    float* __restrict__ o32, ushort* __restrict__ o16)
{
    const int row = blockIdx.x, t = threadIdx.x;
    const size_t base = (size_t)row * 256 + t;

    const float v = (a32 ? a32[base] : bf2f(a16[base])) + bf2f(r16[base]);

    __shared__ float red[4], red2[4];
    const int wid = t >> 6, lane = t & 63;

    float s = v;
    #pragma unroll
    for (int o = 32; o > 0; o >>= 1) s += __shfl_down(s, o);
    if (lane == 0) red[wid] = s;
    __syncthreads();
    const float mean = (red[0] + red[1] + red[2] + red[3]) * (1.f / 256.f);

    const float dv = v - mean;
    float s2 = dv * dv;
    #pragma unroll
    for (int o = 32; o > 0; o >>= 1) s2 += __shfl_down(s2, o);
    if (lane == 0) red2[wid] = s2;
    __syncthreads();
    const float var = (red2[0] + red2[1] + red2[2] + red2[3]) * (1.f / 256.f);

    const float res = dv * rsqrtf(var + EPS_) * g[t] + be[t];
    if (o32) o32[base] = res;
    else     o16[base] = f2bf(res);
}

// ---------------------------------------------------------------------------
extern "C" void kernel_launch(void* const* d_in, const int* in_sizes, int n_in,
                              void* d_out, int out_size, void* d_ws, size_t ws_size,
                              hipStream_t stream)
{
    const float* src    = (const float*)d_in[0];
    const float* pos    = (const float*)d_in[1];
    const float* refp   = (const float*)d_in[2];
    const float* W_off  = (const float*)d_in[5];
    const float* b_off  = (const float*)d_in[6];
    const float* W_attn = (const float*)d_in[7];
    const float* b_attn = (const float*)d_in[8];
    const float* W_val  = (const float*)d_in[9];
    const float* b_val  = (const float*)d_in[10];
    const float* W_out  = (const float*)d_in[11];
    const float* b_out  = (const float*)d_in[12];
    const float* g1     = (const float*)d_in[13];
    const float* be1    = (const float*)d_in[14];
    const float* W_ff1  = (const float*)d_in[15];
    const float* b_ff1  = (const float*)d_in[16];
    const float* W_ff2  = (const float*)d_in[17];
    const float* b_ff2  = (const float*)d_in[18];
    const float* g2     = (const float*)d_in[19];
    const float* be2    = (const float*)d_in[20];
    float* out = (float*)d_out;

    const size_t szMDh = (size_t)M_ * 256 * 2;      // 22,282,240 B
    const size_t szOAh = (size_t)M_ * 384 * 2;      // 33,423,360 B

    char* ws = (char*)d_ws;
    ushort* WT      = (ushort*)ws;
    ushort* WT_val  = WT;
    ushort* WT_oa   = WT + 65536;
    ushort* WT_out  = WT + 163840;
    ushort* WT_ff1  = WT + 229376;
    ushort* WT_ff2  = WT + 491520;
    float*  bias_oa = (float*)(ws + 1507328);

    const size_t o_src  = 2097152;                  // src_bf  -> samp, hbuf
    const size_t o_q    = o_src + szMDh;            // q_bf    -> attn_bf
    const size_t o_val  = o_q   + szMDh;            // value (fp8 head-major)
    const size_t o_oa   = o_val + szMDh;            // offaw [M][384]
    const size_t o_x    = o_oa  + szOAh;            // x_bf
    const size_t o_ffn  = o_x   + szMDh;            // ffn_bf

    ushort* src_bf = (ushort*)(ws + o_src);
    ushort* q_bf   = (ushort*)(ws + o_q);
    ushort* val_f8 = (ushort*)(ws + o_val);         // passed as C, used as fp8
    ushort* offaw  = (ushort*)(ws + o_oa);
    ushort* x_bf   = (ushort*)(ws + o_x);
    ushort* ffn_bf = (ushort*)(ws + o_ffn);
    ushort* samp_bf = src_bf;   // src_bf dead after value GEMM
    ushort* attn_bf = q_bf;     // q_bf dead after offattn GEMM
    ushort* hbuf    = src_bf;   // spans src+q+val+offaw >= M*1024*2

    // 0) all weight converts + bias concat
    wconv_all<<<(753664 + 384 + 255) / 256, 256, 0, stream>>>(
        W_val, W_off, W_attn, W_out, W_ff1, W_ff2, b_off, b_attn, WT, bias_oa);
    // 1) activation converts
    cvt_pair<<<(M_ * 256 / 4 + 255) / 256, 256, 0, stream>>>(src, pos, src_bf, q_bf);
    // 2) value = src @ W_val + b_val  (fp8 head-major output)
    mgemm<<<dim3(2, M_ / 128), 256, 0, stream>>>(src_bf, WT_val, b_val, val_f8, M_, 256, 256, 0, 2);
    // 3) offaw = (src+pos) @ [W_off|W_attn] + [b_off|b_attn]
    mgemm<<<dim3(3, M_ / 128), 256, 0, stream>>>(q_bf, WT_oa, bias_oa, offaw, M_, 384, 256, 0, 0);
    // 4) sampling (softmax inline, owner-level lanes, XCD-chunked)
    sample5<<<M_ / 8, 256, 0, stream>>>((const uint8_t*)val_f8, offaw, refp, samp_bf);
    // 5) attn_out = samp @ W_out + b_out
    mgemm<<<dim3(2, M_ / 128), 256, 0, stream>>>(samp_bf, WT_out, b_out, attn_bf, M_, 256, 256, 0, 0);
    // 6) x = LN(src + attn)
    ln_mix<<<M_, 256, 0, stream>>>(src, nullptr, attn_bf, g1, be1, nullptr, x_bf);
    // 7) FFN1: h = relu(x @ W_ff1 + b_ff1)
    mgemm<<<dim3(8, M_ / 128), 256, 0, stream>>>(x_bf, WT_ff1, b_ff1, hbuf, M_, DFF_, 256, 1, 0);
    // 8) FFN2: ffn = h @ W_ff2 + b_ff2
    mgemm<<<dim3(2, M_ / 128), 256, 0, stream>>>(hbuf, WT_ff2, b_ff2, ffn_bf, M_, 256, DFF_, 0, 0);
    // 9) out = LN(x + ffn)
    ln_mix<<<M_, 256, 0, stream>>>(nullptr, x_bf, ffn_bf, g2, be2, out, nullptr);
}

// Round 6
// 333.214 us; speedup vs baseline: 1.2814x; 1.2814x over previous
//
#include <hip/hip_runtime.h>
#include <cstdint>
#include <cstddef>

#define B_   2
#define S_   21760
#define M_   (B_ * S_)     // 43520
#define D_   256
#define DFF_ 1024
#define EPS_ 1e-5f

typedef __attribute__((ext_vector_type(8))) short short8;
typedef __attribute__((ext_vector_type(4))) float f32x4;
typedef __attribute__((ext_vector_type(2))) float f32x2;

__device__ __forceinline__ ushort f2bf(float f) {
    uint x = __float_as_uint(f);
    return (ushort)((x + 0x7fffu + ((x >> 16) & 1u)) >> 16);
}
__device__ __forceinline__ float bf2f(ushort u) {
    return __uint_as_float(((uint)u) << 16);
}

// ---------------------------------------------------------------------------
// One-shot weight transpose+convert for ALL weights + off/attn bias concat.
// ---------------------------------------------------------------------------
__global__ __launch_bounds__(256) void wconv_all(
    const float* __restrict__ Wval, const float* __restrict__ Woff,
    const float* __restrict__ Wattn, const float* __restrict__ Wout,
    const float* __restrict__ Wff1, const float* __restrict__ Wff2,
    const float* __restrict__ boff, const float* __restrict__ battn,
    ushort* __restrict__ WT, float* __restrict__ bias_oa)
{
    const int i = blockIdx.x * 256 + threadIdx.x;
    if (i < 65536) {
        const int n = i >> 8, k = i & 255;
        WT[i] = f2bf(Wval[(size_t)k * 256 + n]);
    } else if (i < 163840) {
        const int j = i - 65536;
        const int n = j >> 8, k = j & 255;
        WT[i] = (n < 256) ? f2bf(Woff[(size_t)k * 256 + n])
                          : f2bf(Wattn[(size_t)k * 128 + (n - 256)]);
    } else if (i < 229376) {
        const int j = i - 163840;
        const int n = j >> 8, k = j & 255;
        WT[i] = f2bf(Wout[(size_t)k * 256 + n]);
    } else if (i < 491520) {
        const int j = i - 229376;
        const int n = j >> 8, k = j & 255;
        WT[i] = f2bf(Wff1[(size_t)k * 1024 + n]);
    } else if (i < 753664) {
        const int j = i - 491520;
        const int n = j >> 10, k = j & 1023;
        WT[i] = f2bf(Wff2[(size_t)k * 256 + n]);
    } else if (i < 753664 + 384) {
        const int j = i - 753664;
        bias_oa[j] = (j < 256) ? boff[j] : battn[j - 256];
    }
}

// ---------------------------------------------------------------------------
// src_bf = bf16(src); q_bf = bf16(src + pos)
// ---------------------------------------------------------------------------
__global__ __launch_bounds__(256) void cvt_pair(
    const float* __restrict__ src, const float* __restrict__ pos,
    ushort* __restrict__ sb, ushort* __restrict__ qb)
{
    const size_t i = ((size_t)blockIdx.x * 256 + threadIdx.x) * 4;
    if (i >= (size_t)M_ * 256) return;
    const float4 s = *(const float4*)(src + i);
    const float4 p = *(const float4*)(pos + i);
    ushort4 so, qo;
    so.x = f2bf(s.x); so.y = f2bf(s.y); so.z = f2bf(s.z); so.w = f2bf(s.w);
    qo.x = f2bf(s.x + p.x); qo.y = f2bf(s.y + p.y);
    qo.z = f2bf(s.z + p.z); qo.w = f2bf(s.w + p.w);
    *(ushort4*)(sb + i) = so;
    *(ushort4*)(qb + i) = qo;
}

// ---------------------------------------------------------------------------
// bf16 MFMA GEMM: 128x128 tile, BK=32, 4 waves, 4x4 16x16x32 fragments.
// mode 0: C row-major [M][N] bf16.
// mode 2: C = fp8 e4m3, head-major value layout [b][h][loc][32].
// ---------------------------------------------------------------------------
__global__ __launch_bounds__(256) void mgemm(
    const ushort* __restrict__ A, const ushort* __restrict__ WT,
    const float* __restrict__ bias, ushort* __restrict__ C,
    int M, int N, int K, int relu, int mode)
{
    __shared__ __align__(16) ushort Als[128 * 32];
    __shared__ __align__(16) ushort Bls[128 * 32];

    const int tid = threadIdx.x;
    const int wv = tid >> 6, ln = tid & 63;
    const int m0 = blockIdx.y << 7, n0 = blockIdx.x << 7;
    const int wm = wv >> 1, wn = wv & 1;

    const int lrow = ln >> 2, lcol = (ln & 3) * 8;

    f32x4 acc[4][4];
    const f32x4 zz = {0.f, 0.f, 0.f, 0.f};
    #pragma unroll
    for (int i = 0; i < 4; i++)
        #pragma unroll
        for (int j = 0; j < 4; j++) acc[i][j] = zz;

    for (int k0 = 0; k0 < K; k0 += 32) {
        __syncthreads();
        #pragma unroll
        for (int r = 0; r < 2; ++r) {
            const int c = r * 4 + wv;
            const ushort* ga = A + (size_t)(m0 + c * 16 + lrow) * K + k0 + lcol;
            __builtin_amdgcn_global_load_lds(
                (const __attribute__((address_space(1))) uint*)ga,
                (__attribute__((address_space(3))) uint*)(Als + c * 512), 16, 0, 0);
            const ushort* gb = WT + (size_t)(n0 + c * 16 + lrow) * K + k0 + lcol;
            __builtin_amdgcn_global_load_lds(
                (const __attribute__((address_space(1))) uint*)gb,
                (__attribute__((address_space(3))) uint*)(Bls + c * 512), 16, 0, 0);
        }
        __syncthreads();

        const int fr = ln & 15, kb = (ln >> 4) * 8;
        short8 af[4], bfr[4];
        #pragma unroll
        for (int i = 0; i < 4; i++)
            af[i] = *(const short8*)&Als[(wm * 64 + i * 16 + fr) * 32 + kb];
        #pragma unroll
        for (int j = 0; j < 4; j++)
            bfr[j] = *(const short8*)&Bls[(wn * 64 + j * 16 + fr) * 32 + kb];
        #pragma unroll
        for (int i = 0; i < 4; i++)
            #pragma unroll
            for (int j = 0; j < 4; j++)
                acc[i][j] = __builtin_amdgcn_mfma_f32_16x16x32_bf16(
                    af[i], bfr[j], acc[i][j], 0, 0, 0);
    }

    uint8_t* C8 = (uint8_t*)C;
    const int fr = ln & 15, rq = (ln >> 4) * 4;
    #pragma unroll
    for (int j = 0; j < 4; j++) {
        const int col = n0 + wn * 64 + j * 16 + fr;
        const float bv = bias[col];
        #pragma unroll
        for (int i = 0; i < 4; i++) {
            #pragma unroll
            for (int r = 0; r < 4; r++) {
                const int row = m0 + wm * 64 + i * 16 + rq + r;
                float v = acc[i][j][r] + bv;
                if (relu) v = fmaxf(v, 0.f);
                if (mode == 0) {
                    C[(size_t)row * N + col] = f2bf(v);
                } else {
                    const int bb = (row >= S_) ? 1 : 0;
                    const int loc = row - bb * S_;
                    const int hh = col >> 5, ch = col & 31;
                    const int pk = __builtin_amdgcn_cvt_pk_fp8_f32(v, v, 0, false);
                    C8[((size_t)(bb * 8 + hh) * S_ + loc) * 32 + ch] = (uint8_t)(pk & 0xff);
                }
            }
        }
    }
}

// ---------------------------------------------------------------------------
// Deformable sampling v6: cooperative corner-PAIR (64B region) loads.
// Block = 8 queries x 32 lanes; 4-lane group per (q,h). All lanes compute the
// per-sample math redundantly (no shuffles on the load path). Per sample, the
// two x-adjacent corners of each y-row form one 64B region; the group loads
// it as 4x16B. Lane cg covers x-half (cg>>1), channels ((cg&1)*16..+16).
// x-clamping is folded into per-half weights (wA/wB). Final x-half reduction
// via shfl_xor(2). fp8 value; XCD-chunked blockIdx swizzle.
// ---------------------------------------------------------------------------
__global__ __launch_bounds__(256) void sample6(
    const uint8_t* __restrict__ value, const ushort* __restrict__ offaw,
    const float* __restrict__ refp, ushort* __restrict__ samp)
{
    const int nwg = M_ / 8;                       // 5440 (%8 == 0)
    const int bid = blockIdx.x;
    const int wg = (bid & 7) * (nwg >> 3) + (bid >> 3);

    const int t = threadIdx.x;
    const int q = wg * 8 + (t >> 5);
    const int w = t & 31;
    const int h = w >> 2, cg = w & 3;
    const int half = cg >> 1;                     // x-half this lane covers
    const int b = q / S_;

    // ---- softmax over this (q,h)'s 16 logits (lane-redundant, no shuffles)
    const ushort* awq = offaw + (size_t)q * 384 + 256 + h * 16;
    const uint4 la = *(const uint4*)awq;
    const uint4 lb = *(const uint4*)(awq + 8);
    const uint lgu[8] = {la.x, la.y, la.z, la.w, lb.x, lb.y, lb.z, lb.w};
    float aj[16];
    float mx = -1e30f;
    #pragma unroll
    for (int k = 0; k < 8; k++) {
        aj[2 * k]     = bf2f((ushort)(lgu[k] & 0xffff));
        aj[2 * k + 1] = bf2f((ushort)(lgu[k] >> 16));
        mx = fmaxf(mx, fmaxf(aj[2 * k], aj[2 * k + 1]));
    }
    float sum = 0.f;
    #pragma unroll
    for (int s = 0; s < 16; s++) { aj[s] = __expf(aj[s] - mx); sum += aj[s]; }
    const float inv = 1.f / sum;
    #pragma unroll
    for (int s = 0; s < 16; s++) aj[s] *= inv;

    // ---- offsets (16 samples x bf16 pair) and reference points
    const ushort* ofq = offaw + (size_t)q * 384 + h * 32;
    const uint4 o0 = *(const uint4*)ofq;
    const uint4 o1 = *(const uint4*)(ofq + 8);
    const uint4 o2 = *(const uint4*)(ofq + 16);
    const uint4 o3 = *(const uint4*)(ofq + 24);
    const uint ou[16] = {o0.x, o0.y, o0.z, o0.w, o1.x, o1.y, o1.z, o1.w,
                         o2.x, o2.y, o2.z, o2.w, o3.x, o3.y, o3.z, o3.w};
    const float* rp = refp + (size_t)q * 8;
    const float4 rpa = *(const float4*)rp;
    const float4 rpb = *(const float4*)(rp + 4);
    const float rxa[4] = {rpa.x, rpa.z, rpb.x, rpb.z};
    const float rya[4] = {rpa.y, rpa.w, rpb.y, rpb.w};
    const int   stv[4] = {0, 16384, 20480, 21504};

    const uint8_t* vb = value + (size_t)(b * 8 + h) * S_ * 32 + cg * 16;

    f32x2 acc[8];
    #pragma unroll
    for (int k = 0; k < 8; k++) acc[k] = (f32x2){0.f, 0.f};

    #pragma unroll
    for (int l = 0; l < 4; l++) {
        const int Wl = 128 >> l;
        const float fW = (float)Wl;
        const int st = stv[l];
        const float rx = rxa[l], ry = rya[l];

        float rw[8];
        int   rix[8];
        #pragma unroll
        for (int j = 0; j < 4; j++) {
            const int s = l * 4 + j;
            const float ox = bf2f((ushort)(ou[s] & 0xffff));
            const float oy = bf2f((ushort)(ou[s] >> 16));
            const float x = fmaf(rx, fW, ox) - 0.5f;
            const float y = fmaf(ry, fW, oy) - 0.5f;
            const float fx0 = floorf(x), fy0 = floorf(y);
            const float dx = x - fx0, dy = y - fy0;
            const int x0 = (int)fx0, y0 = (int)fy0;

            // x side: region base bx covers x-positions {bx, bx+1}
            const int bx = min(max(x0, 0), Wl - 2);
            const float mwx0 = ((x0 >= 0) & (x0 < Wl)) ? (1.f - dx) : 0.f;
            const float mwx1 = ((x0 + 1 >= 0) & (x0 + 1 < Wl)) ? dx : 0.f;
            const int xc0 = min(max(x0, 0), Wl - 1);
            const int xc1 = min(max(x0 + 1, 0), Wl - 1);
            const float wAx = (xc0 == bx ? mwx0 : 0.f) + (xc1 == bx ? mwx1 : 0.f);
            const float wBx = (xc0 == bx + 1 ? mwx0 : 0.f) + (xc1 == bx + 1 ? mwx1 : 0.f);
            const float wsel = half ? wBx : wAx;

            // y side: two row-regions
            const int yc0 = min(max(y0, 0), Wl - 1);
            const int yc1 = min(max(y0 + 1, 0), Wl - 1);
            const float mwy0 = ((y0 >= 0) & (y0 < Wl)) ? (1.f - dy) : 0.f;
            const float mwy1 = ((y0 + 1 >= 0) & (y0 + 1 < Wl)) ? dy : 0.f;

            const float aw = aj[s] * wsel;
            rw[2 * j]     = aw * mwy0;
            rix[2 * j]    = (st + yc0 * Wl + bx) * 32;
            rw[2 * j + 1] = aw * mwy1;
            rix[2 * j + 1] = (st + yc1 * Wl + bx) * 32;
        }

        #pragma unroll
        for (int r = 0; r < 8; r++) {
            const uint4 u = *(const uint4*)(vb + rix[r]);
            const f32x2 w2 = {rw[r], rw[r]};
            acc[0] += w2 * __builtin_amdgcn_cvt_pk_f32_fp8((int)u.x, false);
            acc[1] += w2 * __builtin_amdgcn_cvt_pk_f32_fp8((int)u.x, true);
            acc[2] += w2 * __builtin_amdgcn_cvt_pk_f32_fp8((int)u.y, false);
            acc[3] += w2 * __builtin_amdgcn_cvt_pk_f32_fp8((int)u.y, true);
            acc[4] += w2 * __builtin_amdgcn_cvt_pk_f32_fp8((int)u.z, false);
            acc[5] += w2 * __builtin_amdgcn_cvt_pk_f32_fp8((int)u.z, true);
            acc[6] += w2 * __builtin_amdgcn_cvt_pk_f32_fp8((int)u.w, false);
            acc[7] += w2 * __builtin_amdgcn_cvt_pk_f32_fp8((int)u.w, true);
        }
    }

    // combine the two x-halves: lanes cg and cg^2 hold the same 16 channels
    #pragma unroll
    for (int k = 0; k < 8; k++) {
        acc[k].x += __shfl_xor(acc[k].x, 2);
        acc[k].y += __shfl_xor(acc[k].y, 2);
    }

    // lane stores its 8-channel slice (static selection)
    f32x2 r0, r1, r2, r3;
    if (half == 0) { r0 = acc[0]; r1 = acc[1]; r2 = acc[2]; r3 = acc[3]; }
    else           { r0 = acc[4]; r1 = acc[5]; r2 = acc[6]; r3 = acc[7]; }

    const int ch_start = (cg & 1) * 16 + half * 8;
    uint4 o;
    o.x = (uint)f2bf(r0.x) | ((uint)f2bf(r0.y) << 16);
    o.y = (uint)f2bf(r1.x) | ((uint)f2bf(r1.y) << 16);
    o.z = (uint)f2bf(r2.x) | ((uint)f2bf(r2.y) << 16);
    o.w = (uint)f2bf(r3.x) | ((uint)f2bf(r3.y) << 16);
    *(uint4*)(samp + (size_t)q * 256 + h * 32 + ch_start) = o;
}

// ---------------------------------------------------------------------------
// LayerNorm over D=256: v = (a32 ? a32 : bf(a16)) + bf(r16); out f32 or bf16.
// ---------------------------------------------------------------------------
__global__ __launch_bounds__(256) void ln_mix(
    const float* __restrict__ a32, const ushort* __restrict__ a16,
    const ushort* __restrict__ r16,
    const float* __restrict__ g, const float* __restrict__ be,
    float* __restrict__ o32, ushort* __restrict__ o16)
{
    const int row = blockIdx.x, t = threadIdx.x;
    const size_t base = (size_t)row * 256 + t;

    const float v = (a32 ? a32[base] : bf2f(a16[base])) + bf2f(r16[base]);

    __shared__ float red[4], red2[4];
    const int wid = t >> 6, lane = t & 63;

    float s = v;
    #pragma unroll
    for (int o = 32; o > 0; o >>= 1) s += __shfl_down(s, o);
    if (lane == 0) red[wid] = s;
    __syncthreads();
    const float mean = (red[0] + red[1] + red[2] + red[3]) * (1.f / 256.f);

    const float dv = v - mean;
    float s2 = dv * dv;
    #pragma unroll
    for (int o = 32; o > 0; o >>= 1) s2 += __shfl_down(s2, o);
    if (lane == 0) red2[wid] = s2;
    __syncthreads();
    const float var = (red2[0] + red2[1] + red2[2] + red2[3]) * (1.f / 256.f);

    const float res = dv * rsqrtf(var + EPS_) * g[t] + be[t];
    if (o32) o32[base] = res;
    else     o16[base] = f2bf(res);
}

// ---------------------------------------------------------------------------
extern "C" void kernel_launch(void* const* d_in, const int* in_sizes, int n_in,
                              void* d_out, int out_size, void* d_ws, size_t ws_size,
                              hipStream_t stream)
{
    const float* src    = (const float*)d_in[0];
    const float* pos    = (const float*)d_in[1];
    const float* refp   = (const float*)d_in[2];
    const float* W_off  = (const float*)d_in[5];
    const float* b_off  = (const float*)d_in[6];
    const float* W_attn = (const float*)d_in[7];
    const float* b_attn = (const float*)d_in[8];
    const float* W_val  = (const float*)d_in[9];
    const float* b_val  = (const float*)d_in[10];
    const float* W_out  = (const float*)d_in[11];
    const float* b_out  = (const float*)d_in[12];
    const float* g1     = (const float*)d_in[13];
    const float* be1    = (const float*)d_in[14];
    const float* W_ff1  = (const float*)d_in[15];
    const float* b_ff1  = (const float*)d_in[16];
    const float* W_ff2  = (const float*)d_in[17];
    const float* b_ff2  = (const float*)d_in[18];
    const float* g2     = (const float*)d_in[19];
    const float* be2    = (const float*)d_in[20];
    float* out = (float*)d_out;

    const size_t szMDh = (size_t)M_ * 256 * 2;      // 22,282,240 B
    const size_t szOAh = (size_t)M_ * 384 * 2;      // 33,423,360 B

    char* ws = (char*)d_ws;
    ushort* WT      = (ushort*)ws;
    ushort* WT_val  = WT;
    ushort* WT_oa   = WT + 65536;
    ushort* WT_out  = WT + 163840;
    ushort* WT_ff1  = WT + 229376;
    ushort* WT_ff2  = WT + 491520;
    float*  bias_oa = (float*)(ws + 1507328);

    const size_t o_src  = 2097152;                  // src_bf  -> samp, hbuf
    const size_t o_q    = o_src + szMDh;            // q_bf    -> attn_bf
    const size_t o_val  = o_q   + szMDh;            // value (fp8 head-major)
    const size_t o_oa   = o_val + szMDh;            // offaw [M][384]
    const size_t o_x    = o_oa  + szOAh;            // x_bf
    const size_t o_ffn  = o_x   + szMDh;            // ffn_bf

    ushort* src_bf = (ushort*)(ws + o_src);
    ushort* q_bf   = (ushort*)(ws + o_q);
    ushort* val_f8 = (ushort*)(ws + o_val);         // passed as C, used as fp8
    ushort* offaw  = (ushort*)(ws + o_oa);
    ushort* x_bf   = (ushort*)(ws + o_x);
    ushort* ffn_bf = (ushort*)(ws + o_ffn);
    ushort* samp_bf = src_bf;   // src_bf dead after value GEMM
    ushort* attn_bf = q_bf;     // q_bf dead after offattn GEMM
    ushort* hbuf    = src_bf;   // spans src+q+val+offaw >= M*1024*2

    // 0) all weight converts + bias concat
    wconv_all<<<(753664 + 384 + 255) / 256, 256, 0, stream>>>(
        W_val, W_off, W_attn, W_out, W_ff1, W_ff2, b_off, b_attn, WT, bias_oa);
    // 1) activation converts
    cvt_pair<<<(M_ * 256 / 4 + 255) / 256, 256, 0, stream>>>(src, pos, src_bf, q_bf);
    // 2) value = src @ W_val + b_val  (fp8 head-major output)
    mgemm<<<dim3(2, M_ / 128), 256, 0, stream>>>(src_bf, WT_val, b_val, val_f8, M_, 256, 256, 0, 2);
    // 3) offaw = (src+pos) @ [W_off|W_attn] + [b_off|b_attn]
    mgemm<<<dim3(3, M_ / 128), 256, 0, stream>>>(q_bf, WT_oa, bias_oa, offaw, M_, 384, 256, 0, 0);
    // 4) sampling (inline softmax, corner-pair loads, XCD-chunked)
    sample6<<<M_ / 8, 256, 0, stream>>>((const uint8_t*)val_f8, offaw, refp, samp_bf);
    // 5) attn_out = samp @ W_out + b_out
    mgemm<<<dim3(2, M_ / 128), 256, 0, stream>>>(samp_bf, WT_out, b_out, attn_bf, M_, 256, 256, 0, 0);
    // 6) x = LN(src + attn)
    ln_mix<<<M_, 256, 0, stream>>>(src, nullptr, attn_bf, g1, be1, nullptr, x_bf);
    // 7) FFN1: h = relu(x @ W_ff1 + b_ff1)
    mgemm<<<dim3(8, M_ / 128), 256, 0, stream>>>(x_bf, WT_ff1, b_ff1, hbuf, M_, DFF_, 256, 1, 0);
    // 8) FFN2: ffn = h @ W_ff2 + b_ff2
    mgemm<<<dim3(2, M_ / 128), 256, 0, stream>>>(hbuf, WT_ff2, b_ff2, ffn_bf, M_, 256, DFF_, 0, 0);
    // 9) out = LN(x + ffn)
    ln_mix<<<M_, 256, 0, stream>>>(nullptr, x_bf, ffn_bf, g2, be2, out, nullptr);
}